// Round 7
// baseline (3656.403 us; speedup 1.0000x reference)
//
#include <hip/hip_runtime.h>
#include <cmath>

#define B_   64
#define T_   512
#define IN_  256
#define H_   512
#define OUT_ 256
#define M_   (B_*T_)   // 32768 rows for the input-projection GEMM

typedef __bf16 bf16x4 __attribute__((ext_vector_type(4)));
typedef __bf16 bf16x8 __attribute__((ext_vector_type(8)));
typedef float  f32x4  __attribute__((ext_vector_type(4)));
typedef unsigned long long u64;

// Split fp32 into bf16 hi (truncated, exact) + bf16 lo (RN of remainder).
static __device__ __forceinline__ void split_f32(float x, __bf16 &hi, __bf16 &lo) {
    unsigned u  = __float_as_uint(x);
    unsigned hu = u & 0xffff0000u;
    hi = __builtin_bit_cast(__bf16, (unsigned short)(hu >> 16));
    lo = (__bf16)(x - __uint_as_float(hu));
}

// ---------------- weight prep ----------------
__global__ void split_arr(const float* __restrict__ src, __bf16* __restrict__ hi,
                          __bf16* __restrict__ lo, int n) {
    int i = blockIdx.x * 256 + threadIdx.x;
    if (i < n) { __bf16 h, l; split_f32(src[i], h, l); hi[i] = h; lo[i] = l; }
}

__global__ void bias_comb(const float* __restrict__ a, const float* __restrict__ b,
                          float* __restrict__ o, int n) {
    int i = blockIdx.x * 256 + threadIdx.x;
    if (i < n) o[i] = a[i] + b[i];
}

// ---------------- xp GEMM: C[M,512] = A[M,K](f32) @ W[512,K]^T + bias ----------------
#define GBM 128
#define GBN 64
#define GBK 32
#define LDA 40

__global__ __launch_bounds__(256) void gemm_xp(
    const float* __restrict__ A, const __bf16* __restrict__ Whi,
    const __bf16* __restrict__ Wlo, const float* __restrict__ bias,
    float* __restrict__ C, int K)
{
    __shared__ __bf16 sAhi[GBM*LDA], sAlo[GBM*LDA], sBhi[GBN*LDA], sBlo[GBN*LDA];
    const int tid = threadIdx.x;
    const int m0 = blockIdx.y * GBM, n0 = blockIdx.x * GBN;
    const int wave = tid >> 6, lane = tid & 63, lm = lane & 15, q = lane >> 4;

    f32x4 acc[2][4];
#pragma unroll
    for (int i = 0; i < 2; ++i)
#pragma unroll
        for (int j = 0; j < 4; ++j) acc[i][j] = (f32x4){0.f,0.f,0.f,0.f};

    for (int k0 = 0; k0 < K; k0 += GBK) {
        __syncthreads();
#pragma unroll
        for (int i = 0; i < 4; ++i) {
            int c = tid + i * 256;
            int row = c >> 3, pos = c & 7;
            float4 v = *(const float4*)(&A[(size_t)(m0+row)*K + k0 + pos*4]);
            __bf16 h0,l0,h1,l1,h2,l2,h3,l3;
            split_f32(v.x,h0,l0); split_f32(v.y,h1,l1);
            split_f32(v.z,h2,l2); split_f32(v.w,h3,l3);
            *(bf16x4*)(&sAhi[row*LDA + pos*4]) = (bf16x4){h0,h1,h2,h3};
            *(bf16x4*)(&sAlo[row*LDA + pos*4]) = (bf16x4){l0,l1,l2,l3};
        }
        {
            int row = tid >> 2, pos = (tid & 3) * 8;
            *(bf16x8*)(&sBhi[row*LDA + pos]) =
                *(const bf16x8*)(&Whi[(size_t)(n0+row)*K + k0 + pos]);
            *(bf16x8*)(&sBlo[row*LDA + pos]) =
                *(const bf16x8*)(&Wlo[(size_t)(n0+row)*K + k0 + pos]);
        }
        __syncthreads();

        bf16x8 ah[2], al[2], bh[4], bl[4];
#pragma unroll
        for (int mt = 0; mt < 2; ++mt) {
            int r = wave*32 + mt*16 + lm;
            ah[mt] = *(const bf16x8*)(&sAhi[r*LDA + q*8]);
            al[mt] = *(const bf16x8*)(&sAlo[r*LDA + q*8]);
        }
#pragma unroll
        for (int nt = 0; nt < 4; ++nt) {
            int r = nt*16 + lm;
            bh[nt] = *(const bf16x8*)(&sBhi[r*LDA + q*8]);
            bl[nt] = *(const bf16x8*)(&sBlo[r*LDA + q*8]);
        }
#pragma unroll
        for (int mt = 0; mt < 2; ++mt)
#pragma unroll
            for (int nt = 0; nt < 4; ++nt) {
                acc[mt][nt] = __builtin_amdgcn_mfma_f32_16x16x32_bf16(ah[mt], bh[nt], acc[mt][nt], 0,0,0);
                acc[mt][nt] = __builtin_amdgcn_mfma_f32_16x16x32_bf16(ah[mt], bl[nt], acc[mt][nt], 0,0,0);
                acc[mt][nt] = __builtin_amdgcn_mfma_f32_16x16x32_bf16(al[mt], bh[nt], acc[mt][nt], 0,0,0);
            }
    }
#pragma unroll
    for (int mt = 0; mt < 2; ++mt)
#pragma unroll
        for (int nt = 0; nt < 4; ++nt)
#pragma unroll
            for (int r = 0; r < 4; ++r) {
                int m = m0 + wave*32 + mt*16 + q*4 + r;
                int n = n0 + nt*16 + lm;
                C[(size_t)m*H_ + n] = acc[mt][nt][r] + bias[n];
            }
}

// ---------------- fused 2-role recurrence, per-wave relaxed signaling ---------------
// 64 blocks = 2 roles x (4 batch-groups x 8 col-blocks).
//  role0: L0 recurrence + inline xp1 projection (W_ih1 streamed from L2, off-path).
//  role1: L1 recurrence (xp1 via seq-embedded u64, self-validating).
// Signaling: per-WAVE flags, RELAXED, stored after a wave-local vmcnt(0) drain
// (ack => data at L3 coherence point; flag issued strictly after => no fence needed).
// Consumers poll all 32 wave-flags of their (role,group) with 64 lanes + __all.
// 2 barriers/step (LDS WAR + RAW); no RELEASE fences; no whole-block drains.
#define RLDA 520     // 512 + 8 pad (bf16)
#define RDEP 8
#define BH   (B_*H_)

#define MMA16(ACC, WH, WL) do { \
    _Pragma("unroll") \
    for (int kt = 0; kt < 16; ++kt) { \
        bf16x8 ah = *(const bf16x8*)(&sAhi[lm*RLDA + kt*32 + q*8]); \
        bf16x8 al = *(const bf16x8*)(&sAlo[lm*RLDA + kt*32 + q*8]); \
        ACC = __builtin_amdgcn_mfma_f32_16x16x32_bf16(ah, WH[kt], ACC, 0,0,0); \
        ACC = __builtin_amdgcn_mfma_f32_16x16x32_bf16(ah, WL[kt], ACC, 0,0,0); \
        ACC = __builtin_amdgcn_mfma_f32_16x16x32_bf16(al, WH[kt], ACC, 0,0,0); \
    } } while (0)

// proj MMA with W streamed from global (L2-resident; not register-pinned)
#define MMA16G(ACC, PH, PL) do { \
    _Pragma("unroll") \
    for (int kt = 0; kt < 16; ++kt) { \
        bf16x8 bh = *(const bf16x8*)(&PH[(size_t)ncol*H_ + kt*32 + q*8]); \
        bf16x8 bl = *(const bf16x8*)(&PL[(size_t)ncol*H_ + kt*32 + q*8]); \
        bf16x8 ah = *(const bf16x8*)(&sAhi[lm*RLDA + kt*32 + q*8]); \
        bf16x8 al = *(const bf16x8*)(&sAlo[lm*RLDA + kt*32 + q*8]); \
        ACC = __builtin_amdgcn_mfma_f32_16x16x32_bf16(ah, bh, ACC, 0,0,0); \
        ACC = __builtin_amdgcn_mfma_f32_16x16x32_bf16(ah, bl, ACC, 0,0,0); \
        ACC = __builtin_amdgcn_mfma_f32_16x16x32_bf16(al, bh, ACC, 0,0,0); \
    } } while (0)

__global__ __launch_bounds__(256, 1) void rnn_fused(
    const float* __restrict__ xp0,                       // [B,T,H] fp32 (gemm output)
    const __bf16* __restrict__ w0hi, const __bf16* __restrict__ w0lo,   // W_hh0 split
    const __bf16* __restrict__ wphi, const __bf16* __restrict__ wplo,   // W_ih1 split
    const __bf16* __restrict__ w1hi, const __bf16* __restrict__ w1lo,   // W_hh1 split
    const float* __restrict__ bias1,                     // bih1+bhh1
    unsigned* __restrict__ h0ring,                       // [8][B*H] packed u32, zeroed
    u64*      __restrict__ xp1ring,                      // [8][B*H] u64 seq|fp32, zeroed
    unsigned* __restrict__ h1ring,                       // [2][B*H] packed u32, zeroed
    float* __restrict__ hlast,                           // [B,H]
    int* __restrict__ flags)                             // [2][4][8][4] wave-flags, zeroed
{
    __shared__ __bf16 sAhi[16*RLDA], sAlo[16*RLDA];
    const int tid  = threadIdx.x;
    const int role = blockIdx.x >> 5;       // 0: L0+proj, 1: L1
    const int sub  = blockIdx.x & 31;
    const int g    = sub >> 3;              // batch group (16 rows)
    const int c    = sub & 7;               // column block (64 cols)
    const int m0g  = g * 16;
    const int n0   = c * 64;
    const int wave = tid >> 6, lane = tid & 63, lm = lane & 15, q = lane >> 4;
    const int ncol = n0 + wave*16 + lm;
    const int srow = tid >> 4, sseg = tid & 15;

    int* const gf     = flags + (role*4 + g)*32;         // this (role,group)'s 32 wave-flags
    int* const myflag = gf + c*4 + wave;                 // this wave's flag
    int* const bp1c   = flags + (1*4 + g)*32 + c*4;      // role1 block c's 4 wave-flags

    // ---- recurrence W fragments, pinned in registers (128 VGPR) ----
    const __bf16* Wh = role ? w1hi : w0hi;
    const __bf16* Wl = role ? w1lo : w0lo;
    bf16x8 wh[16], wl[16];
#pragma unroll
    for (int kt = 0; kt < 16; ++kt) {
        wh[kt] = *(const bf16x8*)(&Wh[(size_t)ncol*H_ + kt*32 + q*8]);
        wl[kt] = *(const bf16x8*)(&Wl[(size_t)ncol*H_ + kt*32 + q*8]);
        asm volatile("" : "+v"(wh[kt]), "+v"(wl[kt]));
    }

    // bulk stage: 16x512 packed u32 (as u64 pairs, agent-scope) -> split LDS planes
    auto stage = [&](const unsigned* base) {
        const u64* row = (const u64*)(base + (size_t)(m0g + srow)*H_);
        __bf16* dh = &sAhi[srow*RLDA];
        __bf16* dl = &sAlo[srow*RLDA];
        u64 vv[16];
#pragma unroll
        for (int j = 0; j < 16; ++j)
            vv[j] = __hip_atomic_load(&row[sseg + j*16], __ATOMIC_RELAXED,
                                      __HIP_MEMORY_SCOPE_AGENT);
#pragma unroll
        for (int j = 0; j < 16; ++j) {
            unsigned pa = (unsigned)vv[j], pb = (unsigned)(vv[j] >> 32);
            int c0 = (sseg + j*16) * 2;
            *(unsigned*)(dh + c0) = (pa >> 16) | (pb & 0xffff0000u);
            *(unsigned*)(dl + c0) = (pa & 0xffffu) | (pb << 16);
        }
    };
    // all-lane poll of this (role,group)'s 32 wave-flags
    auto pollall = [&](int tv) {
        for (;;) {
            int v = __hip_atomic_load(&gf[lane & 31], __ATOMIC_RELAXED,
                                      __HIP_MEMORY_SCOPE_AGENT);
            if (__all(v >= tv)) break;
            __builtin_amdgcn_s_sleep(1);
        }
    };
    // wave-local signal: drain own stores, then relaxed flag (no fence needed)
    auto signal = [&](int tv) {
        asm volatile("s_waitcnt vmcnt(0)" ::: "memory");
        if (lane == 0)
            __hip_atomic_store(myflag, tv, __ATOMIC_RELAXED, __HIP_MEMORY_SCOPE_AGENT);
    };

    if (role == 0) {
        // ---------------- layer-0 recurrence + inline projection ----------------
        const float b1 = bias1[ncol];
        for (int t = 0; t <= T_; ++t) {
            float xr[4];
            if (t < T_) {
#pragma unroll
                for (int r = 0; r < 4; ++r)
                    xr[r] = xp0[((size_t)(m0g + q*4 + r)*T_ + t)*H_ + ncol];
            }
            if (t) pollall(t);                  // peers published h0(t)
            __syncthreads();                    // LDS WAR vs prev proj-mma reads
            stage(h0ring + (size_t)(t & 7)*BH);
            __syncthreads();                    // LDS RAW

            if (t < T_) {                       // recurrence (critical path)
                f32x4 acc = (f32x4){0.f,0.f,0.f,0.f};
                MMA16(acc, wh, wl);
                unsigned* dst = h0ring + (size_t)((t+1) & 7)*BH;
#pragma unroll
                for (int r = 0; r < 4; ++r) {
                    float hv = tanhf(xr[r] + acc[r]);
                    __bf16 hh, hl; split_f32(hv, hh, hl);
                    unsigned pk = ((unsigned)__builtin_bit_cast(unsigned short, hh) << 16)
                                |  (unsigned)__builtin_bit_cast(unsigned short, hl);
                    __hip_atomic_store(&dst[(size_t)(m0g + q*4 + r)*H_ + ncol], pk,
                                       __ATOMIC_RELAXED, __HIP_MEMORY_SCOPE_AGENT);
                }
                signal(t+1);                    // per-wave, barrier-free
            }
            if (t >= 1) {                       // proj of staged h0(t) -> xp1(t-1), seq t
                f32x4 a2 = (f32x4){0.f,0.f,0.f,0.f};
                MMA16G(a2, wphi, wplo);
                if (t >= RDEP + 1) {            // overwrite guard: only block c consumes
                    for (;;) {
                        int v = __hip_atomic_load(&bp1c[lane & 3], __ATOMIC_RELAXED,
                                                  __HIP_MEMORY_SCOPE_AGENT);
                        if (__all(v >= t - RDEP)) break;
                        __builtin_amdgcn_s_sleep(1);
                    }
                }
                u64* dst = xp1ring + (size_t)((t-1) & 7)*BH;
#pragma unroll
                for (int r = 0; r < 4; ++r) {
                    u64 pv = ((u64)(unsigned)t << 32) | __float_as_uint(a2[r] + b1);
                    __hip_atomic_store(&dst[(size_t)(m0g + q*4 + r)*H_ + ncol], pv,
                                       __ATOMIC_RELAXED, __HIP_MEMORY_SCOPE_AGENT);
                }
            }
        }
    } else {
        // ---------------- layer-1 recurrence ----------------
        for (int t = 0; t < T_; ++t) {
            // speculative first-try xp1 loads (validated after the mma via seq)
            const u64* xs = xp1ring + (size_t)(t & 7)*BH;
            u64 xv[4];
#pragma unroll
            for (int r = 0; r < 4; ++r)
                xv[r] = __hip_atomic_load(&xs[(size_t)(m0g + q*4 + r)*H_ + ncol],
                                          __ATOMIC_RELAXED, __HIP_MEMORY_SCOPE_AGENT);
            if (t) pollall(t);                  // peers published h1(t)
            __syncthreads();
            stage(h1ring + (size_t)(t & 1)*BH);
            __syncthreads();

            f32x4 acc = (f32x4){0.f,0.f,0.f,0.f};
            MMA16(acc, wh, wl);

            // finish xp1 poll (4 self-validating words; usually already hit)
#pragma unroll
            for (int r = 0; r < 4; ++r) {
                while ((unsigned)(xv[r] >> 32) != (unsigned)(t+1)) {
                    __builtin_amdgcn_s_sleep(1);
                    xv[r] = __hip_atomic_load(&xs[(size_t)(m0g + q*4 + r)*H_ + ncol],
                                              __ATOMIC_RELAXED, __HIP_MEMORY_SCOPE_AGENT);
                }
            }
            unsigned* dst = h1ring + (size_t)((t+1) & 1)*BH;
#pragma unroll
            for (int r = 0; r < 4; ++r) {
                int m = m0g + q*4 + r;
                float hv = tanhf(__uint_as_float((unsigned)xv[r]) + acc[r]);
                __bf16 hh, hl; split_f32(hv, hh, hl);
                unsigned pk = ((unsigned)__builtin_bit_cast(unsigned short, hh) << 16)
                            |  (unsigned)__builtin_bit_cast(unsigned short, hl);
                __hip_atomic_store(&dst[(size_t)m*H_ + ncol], pk,
                                   __ATOMIC_RELAXED, __HIP_MEMORY_SCOPE_AGENT);
                if (t == T_-1) hlast[(size_t)m*H_ + ncol] = hv;
            }
            signal(t+1);                        // per-wave, barrier-free
        }
    }
}

// ---------------- output projection ----------------
__global__ __launch_bounds__(256) void out_proj(
    const float* __restrict__ hlast, const float* __restrict__ Wout,
    const float* __restrict__ bout, float* __restrict__ out)
{
    __shared__ float sh[H_];
    int b = blockIdx.x;
    for (int i = threadIdx.x; i < H_; i += 256) sh[i] = hlast[(size_t)b*H_ + i];
    __syncthreads();
    int o = threadIdx.x;
    const float* wr = &Wout[(size_t)o*H_];
    float acc = 0.f;
#pragma unroll 4
    for (int k = 0; k < H_; k += 4) {
        float4 wv = *(const float4*)(&wr[k]);
        acc += wv.x*sh[k] + wv.y*sh[k+1] + wv.z*sh[k+2] + wv.w*sh[k+3];
    }
    out[(size_t)b*OUT_ + o] = bout[o] + acc;
}

extern "C" void kernel_launch(void* const* d_in, const int* in_sizes, int n_in,
                              void* d_out, int out_size, void* d_ws, size_t ws_size,
                              hipStream_t stream)
{
    const float* x    = (const float*)d_in[0];
    const float* Wih0 = (const float*)d_in[1];
    const float* Whh0 = (const float*)d_in[2];
    const float* bih0 = (const float*)d_in[3];
    const float* bhh0 = (const float*)d_in[4];
    const float* Wih1 = (const float*)d_in[5];
    const float* Whh1 = (const float*)d_in[6];
    const float* bih1 = (const float*)d_in[7];
    const float* bhh1 = (const float*)d_in[8];
    const float* Wout = (const float*)d_in[9];
    const float* bout = (const float*)d_in[10];

    char* w = (char*)d_ws;
    size_t off = 0;
    auto alloc = [&](size_t bytes) -> void* {
        void* p = w + off; off = (off + bytes + 255) & ~(size_t)255; return p;
    };
    float*  xp     = (float*) alloc((size_t)M_*H_*4);      // 64 MB xp0 (read-only in fused)
    __bf16* wih0hi = (__bf16*)alloc((size_t)H_*IN_*2);
    __bf16* wih0lo = (__bf16*)alloc((size_t)H_*IN_*2);
    __bf16* whh0hi = (__bf16*)alloc((size_t)H_*H_*2);
    __bf16* whh0lo = (__bf16*)alloc((size_t)H_*H_*2);
    __bf16* wih1hi = (__bf16*)alloc((size_t)H_*H_*2);
    __bf16* wih1lo = (__bf16*)alloc((size_t)H_*H_*2);
    __bf16* whh1hi = (__bf16*)alloc((size_t)H_*H_*2);
    __bf16* whh1lo = (__bf16*)alloc((size_t)H_*H_*2);
    float*  bias0  = (float*) alloc(H_*4);
    float*  bias1  = (float*) alloc(H_*4);
    size_t zstart = off;                                   // zero-init region start
    unsigned* h0ring = (unsigned*)alloc((size_t)RDEP*B_*H_*4);  // 1 MB
    u64*      xp1ring= (u64*)     alloc((size_t)RDEP*B_*H_*8);  // 2 MB
    unsigned* h1ring = (unsigned*)alloc((size_t)2*B_*H_*4);     // 256 KB
    int*      flags  = (int*)     alloc(1024);                  // [2][4][8][4] wave-flags
    size_t zlen = off - zstart;
    float*  hlast  = (float*) alloc((size_t)B_*H_*4);

    // zero rings + flags (ws is poisoned before every launch; seq fields must start 0)
    hipMemsetAsync(w + zstart, 0, zlen, stream);

    // weight split + bias combine
    split_arr<<<(H_*IN_+255)/256, 256, 0, stream>>>(Wih0, wih0hi, wih0lo, H_*IN_);
    split_arr<<<(H_*H_ +255)/256, 256, 0, stream>>>(Whh0, whh0hi, whh0lo, H_*H_);
    split_arr<<<(H_*H_ +255)/256, 256, 0, stream>>>(Wih1, wih1hi, wih1lo, H_*H_);
    split_arr<<<(H_*H_ +255)/256, 256, 0, stream>>>(Whh1, whh1hi, whh1lo, H_*H_);
    bias_comb<<<2, 256, 0, stream>>>(bih0, bhh0, bias0, H_);
    bias_comb<<<2, 256, 0, stream>>>(bih1, bhh1, bias1, H_);

    // layer-0 input projection (one big GEMM, K=256)
    dim3 ggrid(H_/GBN, M_/GBM);  // (8, 256)
    gemm_xp<<<ggrid, 256, 0, stream>>>(x, wih0hi, wih0lo, bias0, xp, IN_);

    // fused 2-role pipelined recurrences (L0+proj -> L1), per-wave relaxed signaling
    rnn_fused<<<64, 256, 0, stream>>>(xp, whh0hi, whh0lo, wih1hi, wih1lo,
                                      whh1hi, whh1lo, bias1,
                                      h0ring, xp1ring, h1ring, hlast, flags);

    // output projection
    out_proj<<<B_, 256, 0, stream>>>(hlast, Wout, bout, (float*)d_out);
}

// Round 9
// 2413.344 us; speedup vs baseline: 1.5151x; 1.5151x over previous
//
#include <hip/hip_runtime.h>
#include <cmath>

#define B_   64
#define T_   512
#define IN_  256
#define H_   512
#define OUT_ 256
#define M_   (B_*T_)   // 32768 rows for the input-projection GEMM

typedef __bf16 bf16x4 __attribute__((ext_vector_type(4)));
typedef __bf16 bf16x8 __attribute__((ext_vector_type(8)));
typedef float  f32x4  __attribute__((ext_vector_type(4)));
typedef unsigned long long u64;

// Split fp32 into bf16 hi (truncated, exact) + bf16 lo (RN of remainder).
static __device__ __forceinline__ void split_f32(float x, __bf16 &hi, __bf16 &lo) {
    unsigned u  = __float_as_uint(x);
    unsigned hu = u & 0xffff0000u;
    hi = __builtin_bit_cast(__bf16, (unsigned short)(hu >> 16));
    lo = (__bf16)(x - __uint_as_float(hu));
}

// ---------------- weight prep ----------------
__global__ void split_arr(const float* __restrict__ src, __bf16* __restrict__ hi,
                          __bf16* __restrict__ lo, int n) {
    int i = blockIdx.x * 256 + threadIdx.x;
    if (i < n) { __bf16 h, l; split_f32(src[i], h, l); hi[i] = h; lo[i] = l; }
}

__global__ void bias_comb(const float* __restrict__ a, const float* __restrict__ b,
                          float* __restrict__ o, int n) {
    int i = blockIdx.x * 256 + threadIdx.x;
    if (i < n) o[i] = a[i] + b[i];
}

// ---------------- xp GEMM: C[M,512] = A[M,K](f32) @ W[512,K]^T + bias ----------------
#define GBM 128
#define GBN 64
#define GBK 32
#define LDA 40

__global__ __launch_bounds__(256) void gemm_xp(
    const float* __restrict__ A, const __bf16* __restrict__ Whi,
    const __bf16* __restrict__ Wlo, const float* __restrict__ bias,
    float* __restrict__ C, int K)
{
    __shared__ __bf16 sAhi[GBM*LDA], sAlo[GBM*LDA], sBhi[GBN*LDA], sBlo[GBN*LDA];
    const int tid = threadIdx.x;
    const int m0 = blockIdx.y * GBM, n0 = blockIdx.x * GBN;
    const int wave = tid >> 6, lane = tid & 63, lm = lane & 15, q = lane >> 4;

    f32x4 acc[2][4];
#pragma unroll
    for (int i = 0; i < 2; ++i)
#pragma unroll
        for (int j = 0; j < 4; ++j) acc[i][j] = (f32x4){0.f,0.f,0.f,0.f};

    for (int k0 = 0; k0 < K; k0 += GBK) {
        __syncthreads();
#pragma unroll
        for (int i = 0; i < 4; ++i) {
            int c = tid + i * 256;
            int row = c >> 3, pos = c & 7;
            float4 v = *(const float4*)(&A[(size_t)(m0+row)*K + k0 + pos*4]);
            __bf16 h0,l0,h1,l1,h2,l2,h3,l3;
            split_f32(v.x,h0,l0); split_f32(v.y,h1,l1);
            split_f32(v.z,h2,l2); split_f32(v.w,h3,l3);
            *(bf16x4*)(&sAhi[row*LDA + pos*4]) = (bf16x4){h0,h1,h2,h3};
            *(bf16x4*)(&sAlo[row*LDA + pos*4]) = (bf16x4){l0,l1,l2,l3};
        }
        {
            int row = tid >> 2, pos = (tid & 3) * 8;
            *(bf16x8*)(&sBhi[row*LDA + pos]) =
                *(const bf16x8*)(&Whi[(size_t)(n0+row)*K + k0 + pos]);
            *(bf16x8*)(&sBlo[row*LDA + pos]) =
                *(const bf16x8*)(&Wlo[(size_t)(n0+row)*K + k0 + pos]);
        }
        __syncthreads();

        bf16x8 ah[2], al[2], bh[4], bl[4];
#pragma unroll
        for (int mt = 0; mt < 2; ++mt) {
            int r = wave*32 + mt*16 + lm;
            ah[mt] = *(const bf16x8*)(&sAhi[r*LDA + q*8]);
            al[mt] = *(const bf16x8*)(&sAlo[r*LDA + q*8]);
        }
#pragma unroll
        for (int nt = 0; nt < 4; ++nt) {
            int r = nt*16 + lm;
            bh[nt] = *(const bf16x8*)(&sBhi[r*LDA + q*8]);
            bl[nt] = *(const bf16x8*)(&sBlo[r*LDA + q*8]);
        }
#pragma unroll
        for (int mt = 0; mt < 2; ++mt)
#pragma unroll
            for (int nt = 0; nt < 4; ++nt) {
                acc[mt][nt] = __builtin_amdgcn_mfma_f32_16x16x32_bf16(ah[mt], bh[nt], acc[mt][nt], 0,0,0);
                acc[mt][nt] = __builtin_amdgcn_mfma_f32_16x16x32_bf16(ah[mt], bl[nt], acc[mt][nt], 0,0,0);
                acc[mt][nt] = __builtin_amdgcn_mfma_f32_16x16x32_bf16(al[mt], bh[nt], acc[mt][nt], 0,0,0);
            }
    }
#pragma unroll
    for (int mt = 0; mt < 2; ++mt)
#pragma unroll
        for (int nt = 0; nt < 4; ++nt)
#pragma unroll
            for (int r = 0; r < 4; ++r) {
                int m = m0 + wave*32 + mt*16 + q*4 + r;
                int n = n0 + nt*16 + lm;
                C[(size_t)m*H_ + n] = acc[mt][nt][r] + bias[n];
            }
}

// ---------------- fused 3-role recurrence, pinned W + per-wave relaxed flags --------
// 96 blocks = 3 roles x (4 batch-groups x 8 col-blocks).
//   role0: L0 recurrence (W_hh0 in VGPRs).  publishes h0ring slot (t+1)&7, flag f0.
//   role1: xp1 projection (W_ih1 in VGPRs). consumes h0 (flag fP), publishes xp1
//          (seq-embedded u64, self-validating).
//   role2: L1 recurrence (W_hh1 in VGPRs).  consumes xp1, publishes h1ring, flag f1.
// W pinning: asm "+v" keep-alive INSIDE the t-loop (opaque redefinition each iter
// forbids re-load from memory; rounds 2-7 all streamed 128KB/step from L2, VGPR<=160).
// Signaling: per-WAVE flags, RELAXED, after a wave-local vmcnt(0) drain (ack => data
// at the L3 coherence point). Consumers poll 32 wave-flags with 64 lanes + __all.
#define RLDA 528     // 512 + 16 pad: 264 dwords % 32 == 8 -> staging writes 2-way (free)
#define RDEP 8
#define BH   (B_*H_)

#define KEEPALIVE(WH, WL) do { \
    _Pragma("unroll") \
    for (int kt = 0; kt < 16; ++kt) asm volatile("" : "+v"(WH[kt]), "+v"(WL[kt])); \
    } while (0)

#define MMA16(ACC, WH, WL) do { \
    _Pragma("unroll") \
    for (int kt = 0; kt < 16; ++kt) { \
        bf16x8 ah = *(const bf16x8*)(&sAhi[lm*RLDA + kt*32 + q*8]); \
        bf16x8 al = *(const bf16x8*)(&sAlo[lm*RLDA + kt*32 + q*8]); \
        ACC = __builtin_amdgcn_mfma_f32_16x16x32_bf16(ah, WH[kt], ACC, 0,0,0); \
        ACC = __builtin_amdgcn_mfma_f32_16x16x32_bf16(ah, WL[kt], ACC, 0,0,0); \
        ACC = __builtin_amdgcn_mfma_f32_16x16x32_bf16(al, WH[kt], ACC, 0,0,0); \
    } } while (0)

__global__ __launch_bounds__(256, 1) void rnn_fused(
    const float* __restrict__ xp0,                       // [B,T,H] fp32 (gemm output)
    const __bf16* __restrict__ w0hi, const __bf16* __restrict__ w0lo,   // W_hh0 split
    const __bf16* __restrict__ wphi, const __bf16* __restrict__ wplo,   // W_ih1 split
    const __bf16* __restrict__ w1hi, const __bf16* __restrict__ w1lo,   // W_hh1 split
    const float* __restrict__ bias1,                     // bih1+bhh1
    unsigned* __restrict__ h0ring,                       // [8][B*H] packed u32, zeroed
    u64*      __restrict__ xp1ring,                      // [8][B*H] u64 seq|fp32, zeroed
    unsigned* __restrict__ h1ring,                       // [2][B*H] packed u32, zeroed
    float* __restrict__ hlast,                           // [B,H]
    int* __restrict__ flags)                             // [3][4][8][4] wave-flags, zeroed
{
    __shared__ __bf16 sAhi[16*RLDA], sAlo[16*RLDA];
    const int tid  = threadIdx.x;
    const int role = blockIdx.x >> 5;       // 0: L0, 1: proj, 2: L1
    const int sub  = blockIdx.x & 31;
    const int g    = sub >> 3;              // batch group (16 rows)
    const int c    = sub & 7;               // column block (64 cols)
    const int m0g  = g * 16;
    const int n0   = c * 64;
    const int wave = tid >> 6, lane = tid & 63, lm = lane & 15, q = lane >> 4;
    const int ncol = n0 + wave*16 + lm;
    const int srow = tid >> 4, sseg = tid & 15;

    int* const f0 = flags + (0*4 + g)*32;   // L0 published h0(t+1)
    int* const fP = flags + (1*4 + g)*32;   // proj staged/consumed h0 slot (t+1)
    int* const f1 = flags + (2*4 + g)*32;   // L1 published h1(t+1) (& consumed xp1 t)
    int* const f1c = f1 + c*4;              // L1 block (g,c)'s 4 wave-flags

    // ---- this role's W fragments (128 VGPR), truly pinned via in-loop keep-alive ----
    const __bf16* Wh = (role == 0) ? w0hi : (role == 1) ? wphi : w1hi;
    const __bf16* Wl = (role == 0) ? w0lo : (role == 1) ? wplo : w1lo;
    bf16x8 wh[16], wl[16];
#pragma unroll
    for (int kt = 0; kt < 16; ++kt) {
        wh[kt] = *(const bf16x8*)(&Wh[(size_t)ncol*H_ + kt*32 + q*8]);
        wl[kt] = *(const bf16x8*)(&Wl[(size_t)ncol*H_ + kt*32 + q*8]);
    }

    // bulk stage: 16x512 packed u32 (as u64 pairs, agent-scope) -> split LDS planes
    auto stage = [&](const unsigned* base) {
        const u64* row = (const u64*)(base + (size_t)(m0g + srow)*H_);
        __bf16* dh = &sAhi[srow*RLDA];
        __bf16* dl = &sAlo[srow*RLDA];
        u64 vv[16];
#pragma unroll
        for (int j = 0; j < 16; ++j)
            vv[j] = __hip_atomic_load(&row[sseg + j*16], __ATOMIC_RELAXED,
                                      __HIP_MEMORY_SCOPE_AGENT);
#pragma unroll
        for (int j = 0; j < 16; ++j) {
            unsigned pa = (unsigned)vv[j], pb = (unsigned)(vv[j] >> 32);
            int c0 = (sseg + j*16) * 2;
            *(unsigned*)(dh + c0) = (pa >> 16) | (pb & 0xffff0000u);
            *(unsigned*)(dl + c0) = (pa & 0xffffu) | (pb << 16);
        }
    };
    auto poll32 = [&](int* f, int tv) {     // all 32 wave-flags of a (role,group)
        for (;;) {
            int v = __hip_atomic_load(&f[lane & 31], __ATOMIC_RELAXED,
                                      __HIP_MEMORY_SCOPE_AGENT);
            if (__all(v >= tv)) break;
            __builtin_amdgcn_s_sleep(1);
        }
    };
    auto poll4 = [&](int* f, int tv) {      // one block's 4 wave-flags
        for (;;) {
            int v = __hip_atomic_load(&f[lane & 3], __ATOMIC_RELAXED,
                                      __HIP_MEMORY_SCOPE_AGENT);
            if (__all(v >= tv)) break;
            __builtin_amdgcn_s_sleep(1);
        }
    };
    auto signal = [&](int* fw, int tv) {    // wave-local drain + relaxed flag
        asm volatile("s_waitcnt vmcnt(0)" ::: "memory");
        if (lane == 0)
            __hip_atomic_store(fw, tv, __ATOMIC_RELAXED, __HIP_MEMORY_SCOPE_AGENT);
    };

    if (role == 0) {
        // ---------------- layer-0 recurrence ----------------
        int* const myf = f0 + c*4 + wave;
        for (int t = 0; t < T_; ++t) {
            KEEPALIVE(wh, wl);
            float xr[4];
#pragma unroll
            for (int r = 0; r < 4; ++r)
                xr[r] = xp0[((size_t)(m0g + q*4 + r)*T_ + t)*H_ + ncol];
            int bp = 0;                      // lazy overwrite guard (proj consumed t-7)
            if (t >= 8) bp = __hip_atomic_load(&fP[lane & 31], __ATOMIC_RELAXED,
                                               __HIP_MEMORY_SCOPE_AGENT);
            if (t) poll32(f0, t);            // peers published h0(t)
            __syncthreads();                 // LDS WAR (own prev-MMA reads done)
            stage(h0ring + (size_t)(t & 7)*BH);
            __syncthreads();                 // LDS RAW

            f32x4 acc = (f32x4){0.f,0.f,0.f,0.f};
            MMA16(acc, wh, wl);
            unsigned pk[4];
#pragma unroll
            for (int r = 0; r < 4; ++r) {
                float hv = tanhf(xr[r] + acc[r]);
                __bf16 hh, hl; split_f32(hv, hh, hl);
                pk[r] = ((unsigned)__builtin_bit_cast(unsigned short, hh) << 16)
                      |  (unsigned)__builtin_bit_cast(unsigned short, hl);
            }
            if (t >= 8 && !__all(bp >= t-7)) poll32(fP, t-7);
            unsigned* dst = h0ring + (size_t)((t+1) & 7)*BH;
#pragma unroll
            for (int r = 0; r < 4; ++r)
                __hip_atomic_store(&dst[(size_t)(m0g + q*4 + r)*H_ + ncol], pk[r],
                                   __ATOMIC_RELAXED, __HIP_MEMORY_SCOPE_AGENT);
            signal(myf, t+1);
        }
    } else if (role == 1) {
        // ---------------- layer-1 input projection ----------------
        int* const myf = fP + c*4 + wave;
        const float b1 = bias1[ncol];
        for (int t = 0; t < T_; ++t) {
            KEEPALIVE(wh, wl);
            int bp = 0;                      // lazy guard: L1 consumed xp1 slot t&7
            if (t >= 8) bp = __hip_atomic_load(&f1c[lane & 3], __ATOMIC_RELAXED,
                                               __HIP_MEMORY_SCOPE_AGENT);
            poll32(f0, t+1);                 // h0(t+1) = out0_t available
            __syncthreads();
            stage(h0ring + (size_t)((t+1) & 7)*BH);
            signal(myf, t+1);                // consumption flag (loads retired)
            __syncthreads();

            f32x4 a2 = (f32x4){0.f,0.f,0.f,0.f};
            MMA16(a2, wh, wl);
            if (t >= 8 && !__all(bp >= t-7)) poll4(f1c, t-7);
            u64* dst = xp1ring + (size_t)(t & 7)*BH;
#pragma unroll
            for (int r = 0; r < 4; ++r) {
                u64 pv = ((u64)(unsigned)(t+1) << 32) | __float_as_uint(a2[r] + b1);
                __hip_atomic_store(&dst[(size_t)(m0g + q*4 + r)*H_ + ncol], pv,
                                   __ATOMIC_RELAXED, __HIP_MEMORY_SCOPE_AGENT);
            }
            // no post-store flag: xp1 is self-validating (seq in hi32)
        }
    } else {
        // ---------------- layer-1 recurrence ----------------
        int* const myf = f1 + c*4 + wave;
        for (int t = 0; t < T_; ++t) {
            KEEPALIVE(wh, wl);
            // speculative xp1 loads (validated after the MMA via seq)
            const u64* xs = xp1ring + (size_t)(t & 7)*BH;
            u64 xv[4];
#pragma unroll
            for (int r = 0; r < 4; ++r)
                xv[r] = __hip_atomic_load(&xs[(size_t)(m0g + q*4 + r)*H_ + ncol],
                                          __ATOMIC_RELAXED, __HIP_MEMORY_SCOPE_AGENT);
            if (t) poll32(f1, t);            // peers published h1(t)
            __syncthreads();
            stage(h1ring + (size_t)(t & 1)*BH);
            __syncthreads();

            f32x4 acc = (f32x4){0.f,0.f,0.f,0.f};
            MMA16(acc, wh, wl);
#pragma unroll
            for (int r = 0; r < 4; ++r) {
                while ((unsigned)(xv[r] >> 32) != (unsigned)(t+1)) {
                    __builtin_amdgcn_s_sleep(1);
                    xv[r] = __hip_atomic_load(&xs[(size_t)(m0g + q*4 + r)*H_ + ncol],
                                              __ATOMIC_RELAXED, __HIP_MEMORY_SCOPE_AGENT);
                }
            }
            unsigned* dst = h1ring + (size_t)((t+1) & 1)*BH;
#pragma unroll
            for (int r = 0; r < 4; ++r) {
                int m = m0g + q*4 + r;
                float hv = tanhf(__uint_as_float((unsigned)xv[r]) + acc[r]);
                __bf16 hh, hl; split_f32(hv, hh, hl);
                unsigned pkv = ((unsigned)__builtin_bit_cast(unsigned short, hh) << 16)
                             |  (unsigned)__builtin_bit_cast(unsigned short, hl);
                __hip_atomic_store(&dst[(size_t)m*H_ + ncol], pkv,
                                   __ATOMIC_RELAXED, __HIP_MEMORY_SCOPE_AGENT);
                if (t == T_-1) hlast[(size_t)m*H_ + ncol] = hv;
            }
            signal(myf, t+1);
        }
    }
}

// ---------------- output projection ----------------
__global__ __launch_bounds__(256) void out_proj(
    const float* __restrict__ hlast, const float* __restrict__ Wout,
    const float* __restrict__ bout, float* __restrict__ out)
{
    __shared__ float sh[H_];
    int b = blockIdx.x;
    for (int i = threadIdx.x; i < H_; i += 256) sh[i] = hlast[(size_t)b*H_ + i];
    __syncthreads();
    int o = threadIdx.x;
    const float* wr = &Wout[(size_t)o*H_];
    float acc = 0.f;
#pragma unroll 4
    for (int k = 0; k < H_; k += 4) {
        float4 wv = *(const float4*)(&wr[k]);
        acc += wv.x*sh[k] + wv.y*sh[k+1] + wv.z*sh[k+2] + wv.w*sh[k+3];
    }
    out[(size_t)b*OUT_ + o] = bout[o] + acc;
}

extern "C" void kernel_launch(void* const* d_in, const int* in_sizes, int n_in,
                              void* d_out, int out_size, void* d_ws, size_t ws_size,
                              hipStream_t stream)
{
    const float* x    = (const float*)d_in[0];
    const float* Wih0 = (const float*)d_in[1];
    const float* Whh0 = (const float*)d_in[2];
    const float* bih0 = (const float*)d_in[3];
    const float* bhh0 = (const float*)d_in[4];
    const float* Wih1 = (const float*)d_in[5];
    const float* Whh1 = (const float*)d_in[6];
    const float* bih1 = (const float*)d_in[7];
    const float* bhh1 = (const float*)d_in[8];
    const float* Wout = (const float*)d_in[9];
    const float* bout = (const float*)d_in[10];

    char* w = (char*)d_ws;
    size_t off = 0;
    auto alloc = [&](size_t bytes) -> void* {
        void* p = w + off; off = (off + bytes + 255) & ~(size_t)255; return p;
    };
    float*  xp     = (float*) alloc((size_t)M_*H_*4);      // 64 MB xp0 (read-only in fused)
    __bf16* wih0hi = (__bf16*)alloc((size_t)H_*IN_*2);
    __bf16* wih0lo = (__bf16*)alloc((size_t)H_*IN_*2);
    __bf16* whh0hi = (__bf16*)alloc((size_t)H_*H_*2);
    __bf16* whh0lo = (__bf16*)alloc((size_t)H_*H_*2);
    __bf16* wih1hi = (__bf16*)alloc((size_t)H_*H_*2);
    __bf16* wih1lo = (__bf16*)alloc((size_t)H_*H_*2);
    __bf16* whh1hi = (__bf16*)alloc((size_t)H_*H_*2);
    __bf16* whh1lo = (__bf16*)alloc((size_t)H_*H_*2);
    float*  bias0  = (float*) alloc(H_*4);
    float*  bias1  = (float*) alloc(H_*4);
    size_t zstart = off;                                   // zero-init region start
    unsigned* h0ring = (unsigned*)alloc((size_t)RDEP*B_*H_*4);  // 1 MB
    u64*      xp1ring= (u64*)     alloc((size_t)RDEP*B_*H_*8);  // 2 MB
    unsigned* h1ring = (unsigned*)alloc((size_t)2*B_*H_*4);     // 256 KB
    int*      flags  = (int*)     alloc(1536);                  // [3][4][8][4] wave-flags
    size_t zlen = off - zstart;
    float*  hlast  = (float*) alloc((size_t)B_*H_*4);

    // zero rings + flags (ws is poisoned before every launch; seq fields must start 0)
    hipMemsetAsync(w + zstart, 0, zlen, stream);

    // weight split + bias combine
    split_arr<<<(H_*IN_+255)/256, 256, 0, stream>>>(Wih0, wih0hi, wih0lo, H_*IN_);
    split_arr<<<(H_*H_ +255)/256, 256, 0, stream>>>(Whh0, whh0hi, whh0lo, H_*H_);
    split_arr<<<(H_*H_ +255)/256, 256, 0, stream>>>(Wih1, wih1hi, wih1lo, H_*H_);
    split_arr<<<(H_*H_ +255)/256, 256, 0, stream>>>(Whh1, whh1hi, whh1lo, H_*H_);
    bias_comb<<<2, 256, 0, stream>>>(bih0, bhh0, bias0, H_);
    bias_comb<<<2, 256, 0, stream>>>(bih1, bhh1, bias1, H_);

    // layer-0 input projection (one big GEMM, K=256)
    dim3 ggrid(H_/GBN, M_/GBM);  // (8, 256)
    gemm_xp<<<ggrid, 256, 0, stream>>>(x, wih0hi, wih0lo, bias0, xp, IN_);

    // fused 3-role pipelined recurrences (L0 -> proj -> L1), pinned W + wave flags
    rnn_fused<<<96, 256, 0, stream>>>(xp, whh0hi, whh0lo, wih1hi, wih1lo,
                                      whh1hi, whh1lo, bias1,
                                      h0ring, xp1ring, h1ring, hlast, flags);

    // output projection
    out_proj<<<B_, 256, 0, stream>>>(hlast, Wout, bout, (float*)d_out);
}

// Round 12
// 2391.026 us; speedup vs baseline: 1.5292x; 1.0093x over previous
//
#include <hip/hip_runtime.h>
#include <cmath>

#define B_   64
#define T_   512
#define IN_  256
#define H_   512
#define OUT_ 256
#define M_   (B_*T_)   // 32768 rows for the input-projection GEMM

typedef __bf16 bf16x4 __attribute__((ext_vector_type(4)));
typedef __bf16 bf16x8 __attribute__((ext_vector_type(8)));
typedef float  f32x4  __attribute__((ext_vector_type(4)));
typedef unsigned long long u64;

// Split fp32 into bf16 hi (truncated, exact) + bf16 lo (RN of remainder).
static __device__ __forceinline__ void split_f32(float x, __bf16 &hi, __bf16 &lo) {
    unsigned u  = __float_as_uint(x);
    unsigned hu = u & 0xffff0000u;
    hi = __builtin_bit_cast(__bf16, (unsigned short)(hu >> 16));
    lo = (__bf16)(x - __uint_as_float(hu));
}

// ---------------- weight prep ----------------
__global__ void split_arr(const float* __restrict__ src, __bf16* __restrict__ hi,
                          __bf16* __restrict__ lo, int n) {
    int i = blockIdx.x * 256 + threadIdx.x;
    if (i < n) { __bf16 h, l; split_f32(src[i], h, l); hi[i] = h; lo[i] = l; }
}

__global__ void bias_comb(const float* __restrict__ a, const float* __restrict__ b,
                          float* __restrict__ o, int n) {
    int i = blockIdx.x * 256 + threadIdx.x;
    if (i < n) o[i] = a[i] + b[i];
}

// ---------------- xp GEMM: C[M,512] = A[M,K](f32) @ W[512,K]^T + bias ----------------
#define GBM 128
#define GBN 64
#define GBK 32
#define LDA 40

__global__ __launch_bounds__(256) void gemm_xp(
    const float* __restrict__ A, const __bf16* __restrict__ Whi,
    const __bf16* __restrict__ Wlo, const float* __restrict__ bias,
    float* __restrict__ C, int K)
{
    __shared__ __bf16 sAhi[GBM*LDA], sAlo[GBM*LDA], sBhi[GBN*LDA], sBlo[GBN*LDA];
    const int tid = threadIdx.x;
    const int m0 = blockIdx.y * GBM, n0 = blockIdx.x * GBN;
    const int wave = tid >> 6, lane = tid & 63, lm = lane & 15, q = lane >> 4;

    f32x4 acc[2][4];
#pragma unroll
    for (int i = 0; i < 2; ++i)
#pragma unroll
        for (int j = 0; j < 4; ++j) acc[i][j] = (f32x4){0.f,0.f,0.f,0.f};

    for (int k0 = 0; k0 < K; k0 += GBK) {
        __syncthreads();
#pragma unroll
        for (int i = 0; i < 4; ++i) {
            int c = tid + i * 256;
            int row = c >> 3, pos = c & 7;
            float4 v = *(const float4*)(&A[(size_t)(m0+row)*K + k0 + pos*4]);
            __bf16 h0,l0,h1,l1,h2,l2,h3,l3;
            split_f32(v.x,h0,l0); split_f32(v.y,h1,l1);
            split_f32(v.z,h2,l2); split_f32(v.w,h3,l3);
            *(bf16x4*)(&sAhi[row*LDA + pos*4]) = (bf16x4){h0,h1,h2,h3};
            *(bf16x4*)(&sAlo[row*LDA + pos*4]) = (bf16x4){l0,l1,l2,l3};
        }
        {
            int row = tid >> 2, pos = (tid & 3) * 8;
            *(bf16x8*)(&sBhi[row*LDA + pos]) =
                *(const bf16x8*)(&Whi[(size_t)(n0+row)*K + k0 + pos]);
            *(bf16x8*)(&sBlo[row*LDA + pos]) =
                *(const bf16x8*)(&Wlo[(size_t)(n0+row)*K + k0 + pos]);
        }
        __syncthreads();

        bf16x8 ah[2], al[2], bh[4], bl[4];
#pragma unroll
        for (int mt = 0; mt < 2; ++mt) {
            int r = wave*32 + mt*16 + lm;
            ah[mt] = *(const bf16x8*)(&sAhi[r*LDA + q*8]);
            al[mt] = *(const bf16x8*)(&sAlo[r*LDA + q*8]);
        }
#pragma unroll
        for (int nt = 0; nt < 4; ++nt) {
            int r = nt*16 + lm;
            bh[nt] = *(const bf16x8*)(&sBhi[r*LDA + q*8]);
            bl[nt] = *(const bf16x8*)(&sBlo[r*LDA + q*8]);
        }
#pragma unroll
        for (int mt = 0; mt < 2; ++mt)
#pragma unroll
            for (int nt = 0; nt < 4; ++nt) {
                acc[mt][nt] = __builtin_amdgcn_mfma_f32_16x16x32_bf16(ah[mt], bh[nt], acc[mt][nt], 0,0,0);
                acc[mt][nt] = __builtin_amdgcn_mfma_f32_16x16x32_bf16(ah[mt], bl[nt], acc[mt][nt], 0,0,0);
                acc[mt][nt] = __builtin_amdgcn_mfma_f32_16x16x32_bf16(al[mt], bh[nt], acc[mt][nt], 0,0,0);
            }
    }
#pragma unroll
    for (int mt = 0; mt < 2; ++mt)
#pragma unroll
        for (int nt = 0; nt < 4; ++nt)
#pragma unroll
            for (int r = 0; r < 4; ++r) {
                int m = m0 + wave*32 + mt*16 + q*4 + r;
                int n = n0 + nt*16 + lm;
                C[(size_t)m*H_ + n] = acc[mt][nt][r] + bias[n];
            }
}

// ---------------- fused 2-role recurrence: merged L0+proj, both W pinned ------------
// 64 blocks = 2 roles x (4 batch-groups x 8 col-blocks).
//  role0 t=0..T_ (INCLUSIVE; epilogue t=T_ produces the final xp1(T_-1) — the missing
//  epilogue was r10/r11's deadlock):
//    [t<T_]: poll f0>=t; stage h0(t); MMA W_hh0 -> tanh -> publish h0(t+1);
//            signal f0=t+1 (wave-local vmcnt drain + relaxed flag).
//    [t>=1]: proj MMA (W_ih1, same staged tile) -> xp1(t-1) seq t, fire&forget,
//            shadowed by peers' detect+stage latency.
//  role1 t=0..T_-1: speculative xp1 loads; poll f1>=t; stage h1(t); MMA W_hh1;
//            validate xp1 (seq t+1); tanh -> publish h1(t+1); signal f1=t+1.
// h0 ring needs NO overwrite guard (poll f0>=t implies peers staged slot t-1).
// xp1 guarded lazily by f1 (L1 progress, slack 8). Both W tiles (256 VGPRs) pinned
// via in-loop KEEPALIVE (r9: VGPR 112->180, -11% time); ~320 VGPR ok at 1 block/CU.
#define RLDA 528     // 512 + 16 pad: staging writes 2-way bank (free), reads 8-cyc
#define RDEP 8
#define BH   (B_*H_)

#define KEEPALIVE(WH, WL) do { \
    _Pragma("unroll") \
    for (int kt = 0; kt < 16; ++kt) asm volatile("" : "+v"(WH[kt]), "+v"(WL[kt])); \
    } while (0)

#define MMA16(ACC, WH, WL) do { \
    _Pragma("unroll") \
    for (int kt = 0; kt < 16; ++kt) { \
        bf16x8 ah = *(const bf16x8*)(&sAhi[lm*RLDA + kt*32 + q*8]); \
        bf16x8 al = *(const bf16x8*)(&sAlo[lm*RLDA + kt*32 + q*8]); \
        ACC = __builtin_amdgcn_mfma_f32_16x16x32_bf16(ah, WH[kt], ACC, 0,0,0); \
        ACC = __builtin_amdgcn_mfma_f32_16x16x32_bf16(ah, WL[kt], ACC, 0,0,0); \
        ACC = __builtin_amdgcn_mfma_f32_16x16x32_bf16(al, WH[kt], ACC, 0,0,0); \
    } } while (0)

__global__ __launch_bounds__(256, 1) void rnn_fused(
    const float* __restrict__ xp0,                       // [B,T,H] fp32 (gemm output)
    const __bf16* __restrict__ w0hi, const __bf16* __restrict__ w0lo,   // W_hh0 split
    const __bf16* __restrict__ wphi, const __bf16* __restrict__ wplo,   // W_ih1 split
    const __bf16* __restrict__ w1hi, const __bf16* __restrict__ w1lo,   // W_hh1 split
    const float* __restrict__ bias1,                     // bih1+bhh1
    unsigned* __restrict__ h0ring,                       // [8][B*H] packed u32, zeroed
    u64*      __restrict__ xp1ring,                      // [8][B*H] u64 seq|fp32, zeroed
    unsigned* __restrict__ h1ring,                       // [2][B*H] packed u32, zeroed
    float* __restrict__ hlast,                           // [B,H]
    int* __restrict__ flags)                             // [2][4][8][4] wave-flags, zeroed
{
    __shared__ __bf16 sAhi[16*RLDA], sAlo[16*RLDA];
    const int tid  = threadIdx.x;
    const int role = blockIdx.x >> 5;       // 0: L0+proj, 1: L1
    const int sub  = blockIdx.x & 31;
    const int g    = sub >> 3;              // batch group (16 rows)
    const int c    = sub & 7;               // column block (64 cols)
    const int m0g  = g * 16;
    const int n0   = c * 64;
    const int wave = tid >> 6, lane = tid & 63, lm = lane & 15, q = lane >> 4;
    const int ncol = n0 + wave*16 + lm;
    const int srow = tid >> 4, sseg = tid & 15;

    int* const f0  = flags + (0*4 + g)*32;  // L0 published h0(t+1)
    int* const f1  = flags + (1*4 + g)*32;  // L1 published h1(t+1) (= consumed xp1 t)
    int* const f1c = f1 + c*4;              // L1 block (g,c)'s 4 wave-flags

    // ---- W fragments, pinned via in-loop keep-alive ----
    const __bf16* Wh = role ? w1hi : w0hi;
    const __bf16* Wl = role ? w1lo : w0lo;
    bf16x8 wh[16], wl[16];
#pragma unroll
    for (int kt = 0; kt < 16; ++kt) {
        wh[kt] = *(const bf16x8*)(&Wh[(size_t)ncol*H_ + kt*32 + q*8]);
        wl[kt] = *(const bf16x8*)(&Wl[(size_t)ncol*H_ + kt*32 + q*8]);
    }
    bf16x8 ph[16], pl[16];                  // role0 only: W_ih1
    if (role == 0) {
#pragma unroll
        for (int kt = 0; kt < 16; ++kt) {
            ph[kt] = *(const bf16x8*)(&wphi[(size_t)ncol*H_ + kt*32 + q*8]);
            pl[kt] = *(const bf16x8*)(&wplo[(size_t)ncol*H_ + kt*32 + q*8]);
        }
    }

    // bulk stage: 16x512 packed u32 (as u64 pairs, agent-scope) -> split LDS planes
    auto stage = [&](const unsigned* base) {
        const u64* row = (const u64*)(base + (size_t)(m0g + srow)*H_);
        __bf16* dh = &sAhi[srow*RLDA];
        __bf16* dl = &sAlo[srow*RLDA];
        u64 vv[16];
#pragma unroll
        for (int j = 0; j < 16; ++j)
            vv[j] = __hip_atomic_load(&row[sseg + j*16], __ATOMIC_RELAXED,
                                      __HIP_MEMORY_SCOPE_AGENT);
#pragma unroll
        for (int j = 0; j < 16; ++j) {
            unsigned pa = (unsigned)vv[j], pb = (unsigned)(vv[j] >> 32);
            int c0 = (sseg + j*16) * 2;
            *(unsigned*)(dh + c0) = (pa >> 16) | (pb & 0xffff0000u);
            *(unsigned*)(dl + c0) = (pa & 0xffffu) | (pb << 16);
        }
    };
    auto poll32 = [&](int* f, int tv) {     // all 32 wave-flags of a (role,group)
        for (;;) {
            int v = __hip_atomic_load(&f[lane & 31], __ATOMIC_RELAXED,
                                      __HIP_MEMORY_SCOPE_AGENT);
            if (__all(v >= tv)) break;
            __builtin_amdgcn_s_sleep(1);
        }
    };
    auto poll4 = [&](int* f, int tv) {      // one block's 4 wave-flags
        for (;;) {
            int v = __hip_atomic_load(&f[lane & 3], __ATOMIC_RELAXED,
                                      __HIP_MEMORY_SCOPE_AGENT);
            if (__all(v >= tv)) break;
            __builtin_amdgcn_s_sleep(1);
        }
    };
    auto signal = [&](int* fw, int tv) {    // wave-local drain + relaxed flag
        asm volatile("s_waitcnt vmcnt(0)" ::: "memory");
        if (lane == 0)
            __hip_atomic_store(fw, tv, __ATOMIC_RELAXED, __HIP_MEMORY_SCOPE_AGENT);
    };

    if (role == 0) {
        // ---------------- layer-0 recurrence + shadowed projection ----------------
        int* const myf = f0 + c*4 + wave;
        const float b1 = bias1[ncol];
        for (int t = 0; t <= T_; ++t) {     // INCLUSIVE: t=T_ is the proj epilogue
            KEEPALIVE(wh, wl);
            KEEPALIVE(ph, pl);
            float xr[4];
            if (t < T_) {
#pragma unroll
                for (int r = 0; r < 4; ++r)
                    xr[r] = xp0[((size_t)(m0g + q*4 + r)*T_ + t)*H_ + ncol];
            }
            int bp = 0;                      // lazy xp1-overwrite guard (L1 past t-8)
            if (t >= 9) bp = __hip_atomic_load(&f1c[lane & 3], __ATOMIC_RELAXED,
                                               __HIP_MEMORY_SCOPE_AGENT);
            if (t) poll32(f0, t);            // peers published h0(t)
            __syncthreads();                 // LDS WAR (prev proj-MMA reads done)
            stage(h0ring + (size_t)(t & 7)*BH);
            __syncthreads();                 // LDS RAW

            if (t < T_) {                    // recurrence (critical path)
                f32x4 acc = (f32x4){0.f,0.f,0.f,0.f};
                MMA16(acc, wh, wl);
                unsigned pk[4];
#pragma unroll
                for (int r = 0; r < 4; ++r) {
                    float hv = tanhf(xr[r] + acc[r]);
                    __bf16 hh, hl; split_f32(hv, hh, hl);
                    pk[r] = ((unsigned)__builtin_bit_cast(unsigned short, hh) << 16)
                          |  (unsigned)__builtin_bit_cast(unsigned short, hl);
                }
                unsigned* dst = h0ring + (size_t)((t+1) & 7)*BH;
#pragma unroll
                for (int r = 0; r < 4; ++r)
                    __hip_atomic_store(&dst[(size_t)(m0g + q*4 + r)*H_ + ncol], pk[r],
                                       __ATOMIC_RELAXED, __HIP_MEMORY_SCOPE_AGENT);
                signal(myf, t+1);            // peers can proceed
            }

            // projection of staged h0(t) -> xp1(t-1), seq t  (shadowed by peers' stage)
            if (t >= 1) {
                f32x4 a2 = (f32x4){0.f,0.f,0.f,0.f};
                MMA16(a2, ph, pl);
                if (t >= 9 && !__all(bp >= t-8)) poll4(f1c, t-8);
                u64* xdst = xp1ring + (size_t)((t-1) & 7)*BH;
#pragma unroll
                for (int r = 0; r < 4; ++r) {
                    u64 pv = ((u64)(unsigned)t << 32) | __float_as_uint(a2[r] + b1);
                    __hip_atomic_store(&xdst[(size_t)(m0g + q*4 + r)*H_ + ncol], pv,
                                       __ATOMIC_RELAXED, __HIP_MEMORY_SCOPE_AGENT);
                }
                // no flag: xp1 is self-validating (seq in hi32)
            }
        }
    } else {
        // ---------------- layer-1 recurrence ----------------
        int* const myf = f1 + c*4 + wave;
        for (int t = 0; t < T_; ++t) {
            KEEPALIVE(wh, wl);
            // speculative xp1 loads (validated after the MMA via seq)
            const u64* xs = xp1ring + (size_t)(t & 7)*BH;
            u64 xv[4];
#pragma unroll
            for (int r = 0; r < 4; ++r)
                xv[r] = __hip_atomic_load(&xs[(size_t)(m0g + q*4 + r)*H_ + ncol],
                                          __ATOMIC_RELAXED, __HIP_MEMORY_SCOPE_AGENT);
            if (t) poll32(f1, t);            // peers published h1(t)
            __syncthreads();
            stage(h1ring + (size_t)(t & 1)*BH);
            __syncthreads();

            f32x4 acc = (f32x4){0.f,0.f,0.f,0.f};
            MMA16(acc, wh, wl);
#pragma unroll
            for (int r = 0; r < 4; ++r) {
                while ((unsigned)(xv[r] >> 32) != (unsigned)(t+1)) {
                    __builtin_amdgcn_s_sleep(1);
                    xv[r] = __hip_atomic_load(&xs[(size_t)(m0g + q*4 + r)*H_ + ncol],
                                              __ATOMIC_RELAXED, __HIP_MEMORY_SCOPE_AGENT);
                }
            }
            unsigned* dst = h1ring + (size_t)((t+1) & 1)*BH;
#pragma unroll
            for (int r = 0; r < 4; ++r) {
                int m = m0g + q*4 + r;
                float hv = tanhf(__uint_as_float((unsigned)xv[r]) + acc[r]);
                __bf16 hh, hl; split_f32(hv, hh, hl);
                unsigned pkv = ((unsigned)__builtin_bit_cast(unsigned short, hh) << 16)
                             |  (unsigned)__builtin_bit_cast(unsigned short, hl);
                __hip_atomic_store(&dst[(size_t)m*H_ + ncol], pkv,
                                   __ATOMIC_RELAXED, __HIP_MEMORY_SCOPE_AGENT);
                if (t == T_-1) hlast[(size_t)m*H_ + ncol] = hv;
            }
            signal(myf, t+1);
        }
    }
}

// ---------------- output projection ----------------
__global__ __launch_bounds__(256) void out_proj(
    const float* __restrict__ hlast, const float* __restrict__ Wout,
    const float* __restrict__ bout, float* __restrict__ out)
{
    __shared__ float sh[H_];
    int b = blockIdx.x;
    for (int i = threadIdx.x; i < H_; i += 256) sh[i] = hlast[(size_t)b*H_ + i];
    __syncthreads();
    int o = threadIdx.x;
    const float* wr = &Wout[(size_t)o*H_];
    float acc = 0.f;
#pragma unroll 4
    for (int k = 0; k < H_; k += 4) {
        float4 wv = *(const float4*)(&wr[k]);
        acc += wv.x*sh[k] + wv.y*sh[k+1] + wv.z*sh[k+2] + wv.w*sh[k+3];
    }
    out[(size_t)b*OUT_ + o] = bout[o] + acc;
}

extern "C" void kernel_launch(void* const* d_in, const int* in_sizes, int n_in,
                              void* d_out, int out_size, void* d_ws, size_t ws_size,
                              hipStream_t stream)
{
    const float* x    = (const float*)d_in[0];
    const float* Wih0 = (const float*)d_in[1];
    const float* Whh0 = (const float*)d_in[2];
    const float* bih0 = (const float*)d_in[3];
    const float* bhh0 = (const float*)d_in[4];
    const float* Wih1 = (const float*)d_in[5];
    const float* Whh1 = (const float*)d_in[6];
    const float* bih1 = (const float*)d_in[7];
    const float* bhh1 = (const float*)d_in[8];
    const float* Wout = (const float*)d_in[9];
    const float* bout = (const float*)d_in[10];

    char* w = (char*)d_ws;
    size_t off = 0;
    auto alloc = [&](size_t bytes) -> void* {
        void* p = w + off; off = (off + bytes + 255) & ~(size_t)255; return p;
    };
    float*  xp     = (float*) alloc((size_t)M_*H_*4);      // 64 MB xp0 (read-only in fused)
    __bf16* wih0hi = (__bf16*)alloc((size_t)H_*IN_*2);
    __bf16* wih0lo = (__bf16*)alloc((size_t)H_*IN_*2);
    __bf16* whh0hi = (__bf16*)alloc((size_t)H_*H_*2);
    __bf16* whh0lo = (__bf16*)alloc((size_t)H_*H_*2);
    __bf16* wih1hi = (__bf16*)alloc((size_t)H_*H_*2);
    __bf16* wih1lo = (__bf16*)alloc((size_t)H_*H_*2);
    __bf16* whh1hi = (__bf16*)alloc((size_t)H_*H_*2);
    __bf16* whh1lo = (__bf16*)alloc((size_t)H_*H_*2);
    float*  bias0  = (float*) alloc(H_*4);
    float*  bias1  = (float*) alloc(H_*4);
    size_t zstart = off;                                   // zero-init region start
    unsigned* h0ring = (unsigned*)alloc((size_t)RDEP*B_*H_*4);  // 1 MB
    u64*      xp1ring= (u64*)     alloc((size_t)RDEP*B_*H_*8);  // 2 MB
    unsigned* h1ring = (unsigned*)alloc((size_t)2*B_*H_*4);     // 256 KB
    int*      flags  = (int*)     alloc(1024);                  // [2][4][8][4] wave-flags
    size_t zlen = off - zstart;
    float*  hlast  = (float*) alloc((size_t)B_*H_*4);

    // zero rings + flags (ws is poisoned before every launch; seq fields must start 0)
    hipMemsetAsync(w + zstart, 0, zlen, stream);

    // weight split + bias combine
    split_arr<<<(H_*IN_+255)/256, 256, 0, stream>>>(Wih0, wih0hi, wih0lo, H_*IN_);
    split_arr<<<(H_*H_ +255)/256, 256, 0, stream>>>(Whh0, whh0hi, whh0lo, H_*H_);
    split_arr<<<(H_*H_ +255)/256, 256, 0, stream>>>(Wih1, wih1hi, wih1lo, H_*H_);
    split_arr<<<(H_*H_ +255)/256, 256, 0, stream>>>(Whh1, whh1hi, whh1lo, H_*H_);
    bias_comb<<<2, 256, 0, stream>>>(bih0, bhh0, bias0, H_);
    bias_comb<<<2, 256, 0, stream>>>(bih1, bhh1, bias1, H_);

    // layer-0 input projection (one big GEMM, K=256)
    dim3 ggrid(H_/GBN, M_/GBM);  // (8, 256)
    gemm_xp<<<ggrid, 256, 0, stream>>>(x, wih0hi, wih0lo, bias0, xp, IN_);

    // fused 2-role pipelined recurrences (merged L0+proj -> L1), both W pinned
    rnn_fused<<<64, 256, 0, stream>>>(xp, whh0hi, whh0lo, wih1hi, wih1lo,
                                      whh1hi, whh1lo, bias1,
                                      h0ring, xp1ring, h1ring, hlast, flags);

    // output projection
    out_proj<<<B_, 256, 0, stream>>>(hlast, Wout, bout, (float*)d_out);
}